// Round 11
// baseline (2385.920 us; speedup 1.0000x reference)
//
#include <hip/hip_runtime.h>

// Encoder: 2-layer LSTM (H1=64, H2=32, IN=2), B=512, T=4096, + FC [32->16].
// R11: merged-role waves. R10 lesson: finer wave-splitting duplicates per-wave
// fixed overhead (busy/SIMD-step rose 893->1067) -- occupancy can't beat a
// fixed per-CU workload. So: back to 4 waves/batch (512 blocks x 256 thr,
// 2 waves/SIMD), but EVERY wave does an L1-quarter AND an L2-quarter
// (R10's verified quad-unit / octet-unit layouts). Two independent dot +
// activation chains per wave = 2x ILP to fill R9's 29% idle, with R9's
// per-batch overhead. Weights 56 VGPR/lane -- far under the 128 rung, so
// residency is the allocator default (R2-R7 stripping lesson).
// Also: 2x-unrolled t-loop (compile-time buffer indices), x staged in LDS
// double-buffer (uniform ds_read_b64, no slow readlanes).

#define TT 4096
#define BB 512

typedef float    f4  __attribute__((ext_vector_type(4)));
typedef int      i4  __attribute__((ext_vector_type(4)));
typedef _Float16 h2v __attribute__((ext_vector_type(2)));
typedef _Float16 h8  __attribute__((ext_vector_type(8)));   // 4 VGPRs

__device__ __forceinline__ float fexp2(float x){ return __builtin_amdgcn_exp2f(x); }
__device__ __forceinline__ float frcp (float x){ return __builtin_amdgcn_rcpf(x); }
__device__ __forceinline__ float sigm (float x){ return frcp(1.0f + fexp2(x * -1.4426950408889634f)); }
__device__ __forceinline__ float tanh_(float x){ return 1.0f - 2.0f * frcp(1.0f + fexp2(x * 2.8853900817779268f)); }

// DPP move. 0xB1=[1,0,3,2]; 0x4E=[2,3,0,1]; 0x00/0x55/0xAA/0xFF=quad bcast;
// 0x141=row_half_mirror (j <-> 7-j within 8-lane group).
template<int CTRL>
__device__ __forceinline__ float qperm(float v){
  const int s = __builtin_bit_cast(int, v);
  return __builtin_bit_cast(float, __builtin_amdgcn_update_dpp(s, s, CTRL, 0xF, 0xF, true));
}
__device__ __forceinline__ h2v bch(int s){ return __builtin_bit_cast(h2v, s); }
__device__ __forceinline__ float dot8(h8 a, i4 bi, float c){
  const i4 ai = __builtin_bit_cast(i4, a);
  c = __builtin_amdgcn_fdot2(bch(ai.x), bch(bi.x), c, false);
  c = __builtin_amdgcn_fdot2(bch(ai.y), bch(bi.y), c, false);
  c = __builtin_amdgcn_fdot2(bch(ai.z), bch(bi.z), c, false);
  c = __builtin_amdgcn_fdot2(bch(ai.w), bch(bi.w), c, false);
  return c;
}
__device__ __forceinline__ h8 ldh8(const float* p){
  const f4 a = ((const f4*)p)[0], b = ((const f4*)p)[1];
  h8 r;
  r[0]=(_Float16)a.x; r[1]=(_Float16)a.y; r[2]=(_Float16)a.z; r[3]=(_Float16)a.w;
  r[4]=(_Float16)b.x; r[5]=(_Float16)b.y; r[6]=(_Float16)b.z; r[7]=(_Float16)b.w;
  return r;
}

extern "C" __global__ __launch_bounds__(256) void lstm_enc_kernel(
    const float* __restrict__ x,
    const float* __restrict__ Wih1, const float* __restrict__ Whh1,
    const float* __restrict__ bih1, const float* __restrict__ bhh1,
    const float* __restrict__ Wih2, const float* __restrict__ Whh2,
    const float* __restrict__ bih2, const float* __restrict__ bhh2,
    const float* __restrict__ Wfc,  const float* __restrict__ bfc,
    float* __restrict__ out)
{
    const int tid = threadIdx.x;
    const int l   = tid & 63;
    const int wv  = __builtin_amdgcn_readfirstlane(tid >> 6);   // 0..3, scalar
    const int b   = blockIdx.x;

    // hh[buf][0:64) = h1 halves, hh[buf][64:96) = h2 halves
    __shared__ __align__(16) _Float16 hh[2][96];
    __shared__ __align__(16) float    xs[2][128];   // [buf][64 steps x 2]

    // ---- L1 quarter: quad = unit (16 units/wave) ----
    const int u1  = wv * 16 + (l >> 2);
    const int h1h = l & 1;            // K-half
    const int p1  = (l >> 1) & 1;     // gate-pair
    const int rA1 = (2 * p1) * 64 + u1;
    const int rB1 = rA1 + 64;

    // ---- L2 quarter: octet = unit (8 units/wave) ----
    const int u2  = wv * 8 + (l >> 3);
    const int q2  = l & 3;            // K-quarter
    const int p2  = (l >> 2) & 1;     // gate-pair
    const int rA2 = (2 * p2) * 32 + u2;
    const int rB2 = rA2 + 32;

    // ---- L1 weights: Whh1[row][32*h1h .. +32) -> 4 h8 per row ----
    const float* a1p = Whh1 + rA1 * 64 + 32 * h1h;
    const float* b1p = Whh1 + rB1 * 64 + 32 * h1h;
    h8 w0 = ldh8(a1p+ 0), w1 = ldh8(a1p+ 8), w2 = ldh8(a1p+16), w3 = ldh8(a1p+24);
    h8 w4 = ldh8(b1p+ 0), w5 = ldh8(b1p+ 8), w6 = ldh8(b1p+16), w7 = ldh8(b1p+24);

    // ---- L2 weights: concat(Wih2[row][0:64], Whh2[row][0:32]) [24*q2,+24) ----
#define CAT2(R, F) ((F) < 64 ? (Wih2 + (R)*64 + (F)) : (Whh2 + (R)*32 + (F) - 64))
    const int f0 = 24 * q2;
    h8 v0 = ldh8(CAT2(rA2, f0+0)), v1 = ldh8(CAT2(rA2, f0+8)), v2 = ldh8(CAT2(rA2, f0+16));
    h8 v3 = ldh8(CAT2(rB2, f0+0)), v4 = ldh8(CAT2(rB2, f0+8)), v5 = ldh8(CAT2(rB2, f0+16));
#undef CAT2

    // biases / x-weights counted once (zeroed off the first slice)
    const float bA1  = (h1h == 0) ? (bih1[rA1] + bhh1[rA1]) : 0.f;
    const float bB1  = (h1h == 0) ? (bih1[rB1] + bhh1[rB1]) : 0.f;
    const float wxA0 = (h1h == 0) ? Wih1[rA1*2 + 0] : 0.f;
    const float wxA1 = (h1h == 0) ? Wih1[rA1*2 + 1] : 0.f;
    const float wxB0 = (h1h == 0) ? Wih1[rB1*2 + 0] : 0.f;
    const float wxB1 = (h1h == 0) ? Wih1[rB1*2 + 1] : 0.f;
    const float bA2  = (q2 == 0) ? (bih2[rA2] + bhh2[rA2]) : 0.f;
    const float bB2  = (q2 == 0) ? (bih2[rB2] + bhh2[rB2]) : 0.f;

    // tanh-blend flags: activated gate index == 2 (g-gate)
    const float tf1 = ((l & 3) == 2) ? 1.f : 0.f;
    const float tf2 = (((l & 7) == 4) || ((l & 7) == 6)) ? 1.f : 0.f;

    const float2* xb2 = (const float2*)(x + (size_t)b * (TT * 2));
    float2 vxn = xb2[64 + l];                        // chunk 1 prefetch
    if (wv == 0) ((float2*)xs[0])[l] = xb2[l];       // stage chunk 0
    if (tid < 96) ((int*)hh)[tid] = 0;               // zero both h buffers
    __syncthreads();

    float cc1 = 0.f, cc2 = 0.f;

#define STEP(T, RB, DO_L1) { \
    const int t_ = (T); \
    if (DO_L1) { \
        if ((t_ & 63) == 0) { \
            if (wv == 0) { \
                const int c_ = t_ >> 6; \
                if (t_ + 64 < TT)  ((float2*)xs[(c_ + 1) & 1])[l] = vxn; \
                if (t_ + 128 < TT) vxn = xb2[(c_ + 2) * 64 + l]; \
            } \
        } \
        const float2 xv = ((const float2*)xs[(t_ >> 6) & 1])[t_ & 63]; \
        const i4* hbR = (const i4*)hh[RB]; \
        const i4 H0 = hbR[4*h1h+0], H1 = hbR[4*h1h+1]; \
        const i4 H2 = hbR[4*h1h+2], H3 = hbR[4*h1h+3]; \
        float r0 = bA1, r1 = bB1; \
        r0 = dot8(w0,H0,r0); r0 = dot8(w1,H1,r0); \
        r0 = dot8(w2,H2,r0); r0 = dot8(w3,H3,r0); \
        r1 = dot8(w4,H0,r1); r1 = dot8(w5,H1,r1); \
        r1 = dot8(w6,H2,r1); r1 = dot8(w7,H3,r1); \
        r0 = fmaf(wxA0, xv.x, fmaf(wxA1, xv.y, r0)); \
        r1 = fmaf(wxB0, xv.x, fmaf(wxB1, xv.y, r1)); \
        r0 += qperm<0xB1>(r0); \
        r1 += qperm<0xB1>(r1); \
        const float pre = (l & 1) ? r1 : r0; \
        const float pa  = fmaf(tf1, pre, pre); \
        const float sa  = sigm(pa); \
        const float act = fmaf(tf1, sa - 1.f, sa); \
        const float gi = qperm<0x00>(act); \
        const float gf = qperm<0x55>(act); \
        const float gg = qperm<0xAA>(act); \
        const float go = qperm<0xFF>(act); \
        cc1 = fmaf(gf, cc1, gi * gg); \
        const float hv = go * tanh_(cc1); \
        if ((l & 3) == 0) hh[RB^1][u1] = (_Float16)hv; \
    } \
    if (t_ > 0) { \
        const i4* hbR = (const i4*)hh[RB]; \
        const i4 G0 = hbR[3*q2+0], G1 = hbR[3*q2+1], G2 = hbR[3*q2+2]; \
        float r2 = bA2, r3 = bB2; \
        r2 = dot8(v0,G0,r2); r2 = dot8(v1,G1,r2); r2 = dot8(v2,G2,r2); \
        r3 = dot8(v3,G0,r3); r3 = dot8(v4,G1,r3); r3 = dot8(v5,G2,r3); \
        r2 += qperm<0xB1>(r2); r2 += qperm<0x4E>(r2); \
        r3 += qperm<0xB1>(r3); r3 += qperm<0x4E>(r3); \
        const float pre = (l & 1) ? r3 : r2; \
        const float pa  = fmaf(tf2, pre, pre); \
        const float sa  = sigm(pa); \
        const float act = fmaf(tf2, sa - 1.f, sa); \
        const float vp  = qperm<0xB1>(act); \
        const float eg  = (l & 1) ? vp  : act; \
        const float og  = (l & 1) ? act : vp; \
        const float meg = qperm<0x141>(eg); \
        const float mog = qperm<0x141>(og); \
        const bool hiq  = (l & 4) != 0; \
        const float i2 = hiq ? meg : eg; \
        const float f2 = hiq ? mog : og; \
        const float gv = hiq ? eg  : meg; \
        const float o2 = hiq ? og  : mog; \
        cc2 = fmaf(f2, cc2, i2 * gv); \
        const float hv2 = o2 * tanh_(cc2); \
        if ((l & 7) == 0) hh[RB^1][64 + u2] = (_Float16)hv2; \
    } \
    __syncthreads(); \
}

    // main loop, 2x unrolled: compile-time buffer indices
    for (int t2 = 0; t2 < TT; t2 += 2) {
        STEP(t2,     0, true)
        STEP(t2 + 1, 1, true)
    }
    STEP(TT, 0, false)   // final L2 step (t = TT-1), writes h2 into hh[1]
#undef STEP

    // final h2(TT-1) is in hh[1][64:96)
    if (tid < 16) {
        float s = bfc[tid];
        const float* wr = Wfc + tid * 32;
        #pragma unroll
        for (int k = 0; k < 32; ++k) s = fmaf(wr[k], (float)hh[1][64 + k], s);
        out[b * 16 + tid] = s;
    }
}

extern "C" void kernel_launch(void* const* d_in, const int* in_sizes, int n_in,
                              void* d_out, int out_size, void* d_ws, size_t ws_size,
                              hipStream_t stream) {
    const float* x    = (const float*)d_in[0];
    const float* Wih1 = (const float*)d_in[1];
    const float* Whh1 = (const float*)d_in[2];
    const float* bih1 = (const float*)d_in[3];
    const float* bhh1 = (const float*)d_in[4];
    const float* Wih2 = (const float*)d_in[5];
    const float* Whh2 = (const float*)d_in[6];
    const float* bih2 = (const float*)d_in[7];
    const float* bhh2 = (const float*)d_in[8];
    const float* Wfc  = (const float*)d_in[9];
    const float* bfc  = (const float*)d_in[10];

    hipLaunchKernelGGL(lstm_enc_kernel, dim3(BB), dim3(256), 0, stream,
        x, Wih1, Whh1, bih1, bhh1, Wih2, Whh2, bih2, bhh2, Wfc, bfc,
        (float*)d_out);
}

// Round 12
// 1970.934 us; speedup vs baseline: 1.2106x; 1.2106x over previous
//
#include <hip/hip_runtime.h>

// Encoder: 2-layer LSTM (H1=64, H2=32, IN=2), B=512, T=4096, + FC [32->16].
// R12 = R9 (best: 2145us) with only overhead removal, no structural change:
//  - chunked (64) + 2x-unrolled loop: buffer parity compile-time -> LDS
//    accesses are 4 base pointers + immediate offsets (0 / +192B); the
//    per-step hh[rb] arithmetic and (t&63)==0 branch leave the hot path.
//  - x staged into an LDS double buffer PRE-PACKED fp16 by wave 0 at chunk
//    tops: L1's per-step x cost = 1 uniform ds_read_b32 + 4 fdot2 (replaces
//    2 slow readlanes + 8 fma).
//  - R9's verified role split (waves 2,3 = L1 pair-sliced; waves 0,1 = L2
//    quad-sliced, one step behind), weight scheme (16 shared h8 = 64 VGPR,
//    ternary addresses, resident at VGPR=80), activation paths: unchanged.

#define TT 4096
#define BB 512

typedef float    f4  __attribute__((ext_vector_type(4)));
typedef int      i4  __attribute__((ext_vector_type(4)));
typedef _Float16 h2v __attribute__((ext_vector_type(2)));
typedef _Float16 h8  __attribute__((ext_vector_type(8)));   // 4 VGPRs

__device__ __forceinline__ float fexp2(float x){ return __builtin_amdgcn_exp2f(x); }
__device__ __forceinline__ float frcp (float x){ return __builtin_amdgcn_rcpf(x); }
__device__ __forceinline__ float sigm (float x){ return frcp(1.0f + fexp2(x * -1.4426950408889634f)); }
__device__ __forceinline__ float tanh_(float x){ return 1.0f - 2.0f * frcp(1.0f + fexp2(x * 2.8853900817779268f)); }

// DPP move. 0xB1=[1,0,3,2]; 0x4E=[2,3,0,1]; 0x00/0x55/0xAA/0xFF = quad bcast.
template<int CTRL>
__device__ __forceinline__ float qperm(float v){
  const int s = __builtin_bit_cast(int, v);
  return __builtin_bit_cast(float, __builtin_amdgcn_update_dpp(s, s, CTRL, 0xF, 0xF, true));
}
__device__ __forceinline__ h2v bch(int s){ return __builtin_bit_cast(h2v, s); }
__device__ __forceinline__ float dot8(h8 a, i4 bi, float c){
  const i4 ai = __builtin_bit_cast(i4, a);
  c = __builtin_amdgcn_fdot2(bch(ai.x), bch(bi.x), c, false);
  c = __builtin_amdgcn_fdot2(bch(ai.y), bch(bi.y), c, false);
  c = __builtin_amdgcn_fdot2(bch(ai.z), bch(bi.z), c, false);
  c = __builtin_amdgcn_fdot2(bch(ai.w), bch(bi.w), c, false);
  return c;
}
__device__ __forceinline__ float fdh(int a, int b, float c){
  return __builtin_amdgcn_fdot2(bch(a), bch(b), c, false);
}
__device__ __forceinline__ int pack16(float a, float b){
  h2v p; p.x = (_Float16)a; p.y = (_Float16)b;
  return __builtin_bit_cast(int, p);
}
__device__ __forceinline__ h8 ldh8(const float* p){
  const f4 a = ((const f4*)p)[0], b = ((const f4*)p)[1];
  h8 r;
  r[0]=(_Float16)a.x; r[1]=(_Float16)a.y; r[2]=(_Float16)a.z; r[3]=(_Float16)a.w;
  r[4]=(_Float16)b.x; r[5]=(_Float16)b.y; r[6]=(_Float16)b.z; r[7]=(_Float16)b.w;
  return r;
}

extern "C" __global__ __launch_bounds__(256) void lstm_enc_kernel(
    const float* __restrict__ x,
    const float* __restrict__ Wih1, const float* __restrict__ Whh1,
    const float* __restrict__ bih1, const float* __restrict__ bhh1,
    const float* __restrict__ Wih2, const float* __restrict__ Whh2,
    const float* __restrict__ bih2, const float* __restrict__ bhh2,
    const float* __restrict__ Wfc,  const float* __restrict__ bfc,
    float* __restrict__ out)
{
    const int tid = threadIdx.x;
    const int l   = tid & 63;
    const int wv  = __builtin_amdgcn_readfirstlane(tid >> 6);   // scalar
    const bool isL1 = (wv >= 2);
    const int b   = blockIdx.x;

    // hh[buf][0:64) = h1 halves, hh[buf][64:96) = h2 halves. Contiguous:
    // hh[0][k+96] aliases hh[1][k] (used for immediate-offset writes).
    __shared__ __align__(16) _Float16 hh[2][96];
    __shared__ int xs[2][64];     // packed-fp16 x, one chunk (64 steps) each

    // ---- R9 role indices ----
    const int u1 = (wv & 1) * 32 + (l >> 1);   // L1: pair = unit
    const int s1 = l & 1;                      // L1 K-half
    const int u2 = (wv & 1) * 16 + (l >> 2);   // L2: quad = unit
    const int s2 = l & 3;                      // L2 K-quarter

    // ---- weights: 16 shared h8 (R9 scheme, ternary addresses) ----
    h8 w00,w01,w02,w03, w10,w11,w12,w13, w20,w21,w22,w23, w30,w31,w32,w33;
    float bb0,bb1,bb2,bb3;
    int wxp0,wxp1,wxp2,wxp3;      // packed (wx0,wx1) per gate, s1==0 lanes only

#define LWROW(G, W0,W1,W2,W3, BB_, WXP_) { \
    const int rg1 = (G)*64 + u1; \
    const int rg2 = (G)*32 + u2; \
    const float* a1  = Whh1 + rg1*64 + 32*s1; \
    const float* i2p = Wih2 + rg2*64; \
    const float* h2p = Whh2 + rg2*32; \
    const int f0 = 24*s2, f1 = f0+8, f2c = f0+16; \
    const float* q0 = isL1 ? (a1+ 0) : (f0  < 64 ? i2p+f0  : h2p+f0 -64); \
    const float* q1 = isL1 ? (a1+ 8) : (f1  < 64 ? i2p+f1  : h2p+f1 -64); \
    const float* q2 = isL1 ? (a1+16) : (f2c < 64 ? i2p+f2c : h2p+f2c-64); \
    const float* q3 = isL1 ? (a1+24) : q2; \
    W0 = ldh8(q0); W1 = ldh8(q1); W2 = ldh8(q2); W3 = ldh8(q3); \
    const float bb1v = bih1[rg1] + bhh1[rg1]; \
    const float bb2v = bih2[rg2] + bhh2[rg2]; \
    BB_  = isL1 ? (s1 ? 0.f : bb1v) : (s2 ? 0.f : bb2v); \
    WXP_ = (isL1 && !s1) ? pack16(Wih1[rg1*2], Wih1[rg1*2+1]) : 0; }

    LWROW(0, w00,w01,w02,w03, bb0, wxp0)
    LWROW(1, w10,w11,w12,w13, bb1, wxp1)
    LWROW(2, w20,w21,w22,w23, bb2, wxp2)
    LWROW(3, w30,w31,w32,w33, bb3, wxp3)
#undef LWROW

    const float sf  = (float)s1;                 // L1 tanh blend (g-row on odd lane)
    const float g2t = (s2 == 2) ? 1.f : 0.f;     // L2 tanh blend

    // ---- precomputed LDS access pointers (immediate offsets do the rest) ----
    const i4* hRd = ((const i4*)hh[0]) + 4*s1;   // A-step: [k], B-step: [12+k]
    const i4* qRd = ((const i4*)hh[0]) + 3*s2;
    _Float16* hWr = &hh[0][u1];                  // A-step: [96], B-step: [0]
    _Float16* qWr = &hh[0][64 + u2];

    // ---- x staging (wave 0 only): packed fp16, double-buffered chunks ----
    const float2* xb2 = (const float2*)(x + (size_t)b * (TT * 2));
    float2 vxn = make_float2(0.f, 0.f);
    if (wv == 0) {
        const float2 c0 = xb2[l];
        xs[0][l] = pack16(c0.x, c0.y);           // chunk 0
        vxn = xb2[64 + l];                       // chunk 1 in regs
    }
    if (tid < 96) ((int*)hh)[tid] = 0;           // zero both h buffers
    __syncthreads();

    float cc = 0.f;   // c1 (L1 lanes) / c2 (L2 lanes)

#define STEP(T_, L1EN, RO, WO, XH) { \
    if (isL1) { \
        if (L1EN) { \
            const int xh_ = (XH); \
            const i4 H0 = hRd[(RO)+0], H1 = hRd[(RO)+1]; \
            const i4 H2 = hRd[(RO)+2], H3 = hRd[(RO)+3]; \
            float r0 = bb0, r1 = bb1, r2 = bb2, r3 = bb3; \
            r0 = dot8(w00,H0,r0); r0 = dot8(w01,H1,r0); r0 = dot8(w02,H2,r0); r0 = dot8(w03,H3,r0); \
            r1 = dot8(w10,H0,r1); r1 = dot8(w11,H1,r1); r1 = dot8(w12,H2,r1); r1 = dot8(w13,H3,r1); \
            r2 = dot8(w20,H0,r2); r2 = dot8(w21,H1,r2); r2 = dot8(w22,H2,r2); r2 = dot8(w23,H3,r2); \
            r3 = dot8(w30,H0,r3); r3 = dot8(w31,H1,r3); r3 = dot8(w32,H2,r3); r3 = dot8(w33,H3,r3); \
            r0 = fdh(wxp0, xh_, r0); r1 = fdh(wxp1, xh_, r1); \
            r2 = fdh(wxp2, xh_, r2); r3 = fdh(wxp3, xh_, r3); \
            r0 += qperm<0xB1>(r0); r1 += qperm<0xB1>(r1); \
            r2 += qperm<0xB1>(r2); r3 += qperm<0xB1>(r3); \
            const float pe0 = s1 ? r2 : r0; \
            const float pe1 = s1 ? r3 : r1; \
            const float pb  = fmaf(sf, pe0, pe0); \
            const float sa  = sigm(pb); \
            const float v0  = fmaf(sf, sa - 1.f, sa); \
            const float v1  = sigm(pe1); \
            const float o0  = qperm<0xB1>(v0); \
            const float o1  = qperm<0xB1>(v1); \
            const float gi = s1 ? o0 : v0, gf = s1 ? o1 : v1; \
            const float gg = s1 ? v0 : o0, go = s1 ? v1 : o1; \
            cc = fmaf(gf, cc, gi * gg); \
            const float h1v = go * tanh_(cc); \
            if (!s1) hWr[WO] = (_Float16)h1v; \
        } \
    } else if ((T_) > 0) { \
        const i4 G0 = qRd[(RO)+0], G1 = qRd[(RO)+1], G2 = qRd[(RO)+2]; \
        float r0 = bb0, r1 = bb1, r2 = bb2, r3 = bb3; \
        r0 = dot8(w00,G0,r0); r0 = dot8(w01,G1,r0); r0 = dot8(w02,G2,r0); \
        r1 = dot8(w10,G0,r1); r1 = dot8(w11,G1,r1); r1 = dot8(w12,G2,r1); \
        r2 = dot8(w20,G0,r2); r2 = dot8(w21,G1,r2); r2 = dot8(w22,G2,r2); \
        r3 = dot8(w30,G0,r3); r3 = dot8(w31,G1,r3); r3 = dot8(w32,G2,r3); \
        r0 += qperm<0xB1>(r0); r0 += qperm<0x4E>(r0); \
        r1 += qperm<0xB1>(r1); r1 += qperm<0x4E>(r1); \
        r2 += qperm<0xB1>(r2); r2 += qperm<0x4E>(r2); \
        r3 += qperm<0xB1>(r3); r3 += qperm<0x4E>(r3); \
        const float pre = (s2==0) ? r0 : (s2==1) ? r1 : (s2==2) ? r2 : r3; \
        const float p2  = fmaf(g2t, pre, pre); \
        const float sv  = sigm(p2); \
        const float act = fmaf(g2t, sv - 1.f, sv); \
        const float i2 = qperm<0x00>(act); \
        const float f2 = qperm<0x55>(act); \
        const float gv = qperm<0xAA>(act); \
        const float o2 = qperm<0xFF>(act); \
        cc = fmaf(f2, cc, i2 * gv); \
        const float h2v_ = o2 * tanh_(cc); \
        if (s2 == 0) qWr[WO] = (_Float16)h2v_; \
    } \
    __syncthreads(); \
}

    for (int c = 0; c < 64; ++c) {
        if (wv == 0) {
            // stage chunk c+1 (held in vxn), prefetch chunk c+2
            if (c + 1 < 64) xs[(c + 1) & 1][l] = pack16(vxn.x, vxn.y);
            if (c + 2 < 64) vxn = xb2[(c + 2) * 64 + l];
        }
        const int* xc = xs[c & 1];
        const int base = c << 6;
        for (int tt = 0; tt < 64; tt += 2) {
            STEP(base + tt,     1, 0,  96, xc[tt])      // rb=0: read hh[0], write hh[1]
            STEP(base + tt + 1, 1, 12, 0,  xc[tt + 1])  // rb=1: read hh[1], write hh[0]
        }
    }
    STEP(TT, 0, 0, 96, 0)   // final L2 step (t=TT-1): read hh[0], write hh[1]
#undef STEP

    // final h2(TT-1) is in hh[1][64:96)
    if (tid < 16) {
        float s = bfc[tid];
        const float* wr = Wfc + tid * 32;
        #pragma unroll
        for (int k = 0; k < 32; ++k) s = fmaf(wr[k], (float)hh[1][64 + k], s);
        out[b * 16 + tid] = s;
    }
}

extern "C" void kernel_launch(void* const* d_in, const int* in_sizes, int n_in,
                              void* d_out, int out_size, void* d_ws, size_t ws_size,
                              hipStream_t stream) {
    const float* x    = (const float*)d_in[0];
    const float* Wih1 = (const float*)d_in[1];
    const float* Whh1 = (const float*)d_in[2];
    const float* bih1 = (const float*)d_in[3];
    const float* bhh1 = (const float*)d_in[4];
    const float* Wih2 = (const float*)d_in[5];
    const float* Whh2 = (const float*)d_in[6];
    const float* bih2 = (const float*)d_in[7];
    const float* bhh2 = (const float*)d_in[8];
    const float* Wfc  = (const float*)d_in[9];
    const float* bfc  = (const float*)d_in[10];

    hipLaunchKernelGGL(lstm_enc_kernel, dim3(BB), dim3(256), 0, stream,
        x, Wih1, Whh1, bih1, bhh1, Wih2, Whh2, bih2, bhh2, Wfc, bfc,
        (float*)d_out);
}